// Round 4
// baseline (340.487 us; speedup 1.0000x reference)
//
#include <hip/hip_runtime.h>

// BinaryDense: out = sign(x) @ sign(w). x[8192,4096] f32, w[4096,4096] f32, out f32.
// fp4 e2m1 nibbles {-1,0,+1} = {0xA,0x0,0x2}; MX-scaled fp4 MFMA (scales=1.0). Exact.
// Round 4: LDS-FREE GEMM. Operands pre-packed in MFMA fragment order:
//   granule g(rowgrp, kg, rl) at offset ((rowgrp*128 + kg)*32 + rl)*16
//   (rowgrp = row>>5, kg = k_elem>>5, rl = row&31; 16B granule = 32 k-nibbles).
// A wave's fragment load = base + lane*16 -> one coalesced dwordx4 (two 512B
// segments), matching the verified operand mapping row=l&31, k=(l>>5)*32+[0,32).
// No LDS, no barriers: register-double-buffered prefetch; compiler emits
// fine-grained vmcnt since no s_barrier forces a drain.

#define M_DIM 8192
#define K_DIM 4096
#define N_DIM 4096
#define KB2   (K_DIM / 2)     // packed bytes per row = 2048
#define NKG   (KB2 / 16)      // 128 granules per row
#define GRPB  (NKG * 32 * 16) // bytes per 32-row group = 65536
#define NK    (K_DIM / 128)   // 32 K-iterations (BK=128)

typedef int   v4i  __attribute__((ext_vector_type(4)));
typedef int   v8i  __attribute__((ext_vector_type(8)));
typedef float v16f __attribute__((ext_vector_type(16)));

__device__ __forceinline__ unsigned int nib4(float x) {
    // fp4 e2m1: +1.0 -> 0b0010, -1.0 -> 0b1010, 0 -> 0b0000
    return x > 0.0f ? 0x2u : (x < 0.0f ? 0xAu : 0x0u);
}

// ---- fused pack ----
// blocks [0,1024): pack x -> fragment order. block = (mg = id>>2, kslice = id&3).
// blocks [1024,3072): pack w (k-major) -> wT fragment order via LDS transpose.
__global__ __launch_bounds__(256) void pack_both(const float* __restrict__ x,
                                                 unsigned char* __restrict__ xq,
                                                 const float* __restrict__ w,
                                                 unsigned char* __restrict__ wq) {
    const int t = threadIdx.x;
    if (blockIdx.x < 1024u) {
        const int mg = blockIdx.x >> 2;          // 32-row group, 0..255
        const int ks = blockIdx.x & 3;           // k-slice
        const int r  = t & 31;
        const int kgbase = ks * 32 + (t >> 5) * 4;
        const float* row = x + (size_t)(mg * 32 + r) * K_DIM;
        unsigned char* outb = xq + (size_t)mg * GRPB + r * 16;
#pragma unroll
        for (int j = 0; j < 4; ++j) {
            const int kg = kgbase + j;
            union { unsigned char b[16]; int4 v; } u;
#pragma unroll
            for (int i = 0; i < 8; ++i) {
                float4 f = *(const float4*)(row + kg * 32 + i * 4);
                u.b[i * 2]     = (unsigned char)(nib4(f.x) | (nib4(f.y) << 4));
                u.b[i * 2 + 1] = (unsigned char)(nib4(f.z) | (nib4(f.w) << 4));
            }
            *(int4*)(outb + (size_t)kg * 512) = u.v;
        }
        return;
    }
    // ---- pack w: 64k x 128n tile, transpose via LDS, write fragment order ----
    __shared__ unsigned char sT[64][132];
    const unsigned id = blockIdx.x - 1024u;
    const int n0 = (int)(id & 31) * 128;
    const int kb = (int)(id >> 5);        // 64-k tile -> kg pair {kb*2, kb*2+1}
    const int k0 = kb * 64;

    const int cq = t & 31;   // float4 column
    const int r0 = t >> 5;   // 0..7
#pragma unroll
    for (int p = 0; p < 8; ++p) {
        int r = r0 + 8 * p;
        float4 f = *(const float4*)(w + (size_t)(k0 + r) * N_DIM + n0 + cq * 4);
        uchar4 c;
        c.x = (unsigned char)nib4(f.x);
        c.y = (unsigned char)nib4(f.y);
        c.z = (unsigned char)nib4(f.z);
        c.w = (unsigned char)nib4(f.w);
        *(uchar4*)(&sT[r][cq * 4]) = c;
    }
    __syncthreads();

    const int n  = t >> 1;   // 0..127
    const int kq = t & 1;    // which 32-k granule of this 64-k tile
    union { unsigned char b[16]; int4 v; } u;
#pragma unroll
    for (int j = 0; j < 16; ++j) {
        unsigned lo = sT[kq * 32 + 2 * j][n];
        unsigned hi = sT[kq * 32 + 2 * j + 1][n];
        u.b[j] = (unsigned char)(lo | (hi << 4));
    }
    const int ng = (n0 >> 5) + (n >> 5);
    const int kg = kb * 2 + kq;
    const int rl = n & 31;
    *(int4*)(wq + (size_t)ng * GRPB + (size_t)kg * 512 + rl * 16) = u.v;
}

__device__ __forceinline__ v8i widen(v4i x) {
    v8i r;
    r[0] = x[0]; r[1] = x[1]; r[2] = x[2]; r[3] = x[3];
    r[4] = 0; r[5] = 0; r[6] = 0; r[7] = 0;
    return r;
}

// ---- fp4 MFMA GEMM, LDS-free ----
// 128x128 tile, BK=128, 4 waves 2x2, each wave 2x2 of 32x32x64 mfma.
__global__ __launch_bounds__(256) void bgemm_fp4(const unsigned char* __restrict__ A,
                                                 const unsigned char* __restrict__ B,
                                                 float* __restrict__ C) {
    const int tid  = threadIdx.x;
    const int lane = tid & 63;
    const int wave = tid >> 6;
    const int wm   = wave >> 1;
    const int wn   = wave & 1;
    const int l31  = lane & 31;
    const int lhi  = lane >> 5;

    const int m0 = blockIdx.y * 128;
    const int n0 = blockIdx.x * 128;

    // Fragment stream base pointers: frag(t, ks, kt) at p[t] + kt*2048 + ks*1024.
    const unsigned char* pA[2];
    const unsigned char* pB[2];
#pragma unroll
    for (int tm = 0; tm < 2; ++tm)
        pA[tm] = A + (size_t)((m0 >> 5) + wm * 2 + tm) * GRPB + lane * 16;
#pragma unroll
    for (int tn = 0; tn < 2; ++tn)
        pB[tn] = B + (size_t)((n0 >> 5) + wn * 2 + tn) * GRPB + lane * 16;

    v16f acc[2][2] = {};
    v4i a[2][2][2], b[2][2][2];   // [buf][ks][t]

    auto loadTile = [&](int buf, int kt) {
        const int off = kt * 2048;
#pragma unroll
        for (int ks = 0; ks < 2; ++ks)
#pragma unroll
            for (int tt = 0; tt < 2; ++tt) {
                a[buf][ks][tt] = *(const v4i*)(pA[tt] + off + ks * 1024);
                b[buf][ks][tt] = *(const v4i*)(pB[tt] + off + ks * 1024);
            }
    };
    auto compute = [&](int buf) {
#pragma unroll
        for (int ks = 0; ks < 2; ++ks)
#pragma unroll
            for (int tm = 0; tm < 2; ++tm)
#pragma unroll
                for (int tn = 0; tn < 2; ++tn)
                    acc[tm][tn] = __builtin_amdgcn_mfma_scale_f32_32x32x64_f8f6f4(
                        widen(a[buf][ks][tm]), widen(b[buf][ks][tn]), acc[tm][tn],
                        4, 4,                  // cbsz=FP4, blgp=FP4
                        0, 0x7F7F7F7F,         // opsel_a, scale_a (e8m0 1.0)
                        0, 0x7F7F7F7F);        // opsel_b, scale_b
    };

    loadTile(0, 0);
    for (int kt = 0; kt < NK; ++kt) {
        const int cur = kt & 1;
        if (kt + 1 < NK) loadTile(cur ^ 1, kt + 1);
        compute(cur);
    }

    // Epilogue: C/D 32x32 layout: col = lane&31, row = (r&3) + 8*(r>>2) + 4*lhi
#pragma unroll
    for (int tm = 0; tm < 2; ++tm) {
#pragma unroll
        for (int tn = 0; tn < 2; ++tn) {
            const int col  = n0 + wn * 64 + tn * 32 + l31;
            const int rowb = m0 + wm * 64 + tm * 32 + 4 * lhi;
#pragma unroll
            for (int r = 0; r < 16; ++r) {
                int row = rowb + (r & 3) + 8 * (r >> 2);
                __builtin_nontemporal_store(acc[tm][tn][r], &C[(size_t)row * N_DIM + col]);
            }
        }
    }
}

extern "C" void kernel_launch(void* const* d_in, const int* in_sizes, int n_in,
                              void* d_out, int out_size, void* d_ws, size_t ws_size,
                              hipStream_t stream) {
    const float* x = (const float*)d_in[0];   // [8192, 4096]
    const float* w = (const float*)d_in[1];   // [4096, 4096]
    float* out = (float*)d_out;               // [8192, 4096]

    unsigned char* xq = (unsigned char*)d_ws;                 // 16 MB packed x (frag order)
    unsigned char* wq = xq + (size_t)M_DIM * KB2;             // 8 MB packed wT (frag order)

    // 1024 x-pack blocks + 2048 w-pack blocks, one dispatch
    pack_both<<<dim3(1024 + 2048), dim3(256), 0, stream>>>(x, xq, w, wq);
    bgemm_fp4<<<dim3(N_DIM / 128, M_DIM / 128), dim3(256), 0, stream>>>(xq, wq, out);
}